// Round 2
// baseline (265.267 us; speedup 1.0000x reference)
//
#include <hip/hip_runtime.h>
#include <hip/hip_bf16.h>
#include <math.h>

#define N_ROWS 8192
#define DIM 1024
#define BM 128
#define BN 128
#define BK 64

typedef __attribute__((ext_vector_type(8))) __bf16 bf16x8;
typedef __attribute__((ext_vector_type(4))) float f32x4;

__device__ __forceinline__ unsigned short f2bf(float f) {
    unsigned u = __builtin_bit_cast(unsigned, f);
    u += 0x7fffu + ((u >> 16) & 1u);
    return (unsigned short)(u >> 16);
}

// ---------------- Kernel 1: row L2-normalize fp32 -> bf16 ----------------
// 256 threads = 4 waves, one wave per row.
__global__ __launch_bounds__(256) void cl_norm_kernel(
    const float* __restrict__ z, unsigned short* __restrict__ zn) {
    const int row  = blockIdx.x * 4 + (threadIdx.x >> 6);
    const int lane = threadIdx.x & 63;
    const float* zr = z + (size_t)row * DIM;
    float4 v[4];
    float ss = 0.f;
#pragma unroll
    for (int j = 0; j < 4; ++j) {
        v[j] = *reinterpret_cast<const float4*>(zr + j * 256 + lane * 4);
        ss += v[j].x * v[j].x + v[j].y * v[j].y + v[j].z * v[j].z + v[j].w * v[j].w;
    }
#pragma unroll
    for (int m = 1; m < 64; m <<= 1) ss += __shfl_xor(ss, m, 64);
    const float scale = 1.0f / fmaxf(sqrtf(ss), 1e-8f);
    unsigned short* zo = zn + (size_t)row * DIM;
#pragma unroll
    for (int j = 0; j < 4; ++j) {
        ushort4 o;
        o.x = f2bf(v[j].x * scale);
        o.y = f2bf(v[j].y * scale);
        o.z = f2bf(v[j].z * scale);
        o.w = f2bf(v[j].w * scale);
        *reinterpret_cast<ushort4*>(zo + j * 256 + lane * 4) = o;
    }
}

// ---------------- Kernel 2: fused sim-tile GEMM + partial LSE ----------------
// Grid (64, 64): blockIdx.x = col tile ci, blockIdx.y = row tile ri.
// 256 threads = 4 waves in 2x2; each wave owns a 64x64 sub-tile (4x4 frags of 16x16x32 bf16 MFMA).
// Epilogue: per-row (max, sum exp) over each 64-col chunk -> part[chunk][row]; pos logit extraction.
__global__ __launch_bounds__(256) void cl_simlse_kernel(
    const unsigned short* __restrict__ zn,
    float2* __restrict__ part,      // [128 chunks][8192 rows]
    float* __restrict__ pos) {      // [8192]
    __shared__ unsigned short As[BM * BK];
    __shared__ unsigned short Bs[BN * BK];

    const int t    = threadIdx.x;
    const int lane = t & 63;
    const int wid  = t >> 6;
    const int wr   = wid >> 1;
    const int wc   = wid & 1;
    const int ci   = blockIdx.x;
    const int ri   = blockIdx.y;
    const int rbase = ri * BM;
    const int cbase = ci * BN;

    const f32x4 zero4 = {0.f, 0.f, 0.f, 0.f};
    f32x4 acc[4][4];
#pragma unroll
    for (int m = 0; m < 4; ++m)
#pragma unroll
        for (int n = 0; n < 4; ++n) acc[m][n] = zero4;

    for (int kt = 0; kt < DIM / BK; ++kt) {
        const int k0 = kt * BK;
        // stage A/B tiles: 128x64 bf16 each, 16B per lane, 4 issues per tile
#pragma unroll
        for (int it = 0; it < 4; ++it) {
            const int e   = (it * 256 + t) * 8;  // element offset within tile
            const int row = e >> 6;
            const int k   = e & 63;
            const unsigned short* ga = zn + (size_t)(rbase + row) * DIM + k0 + k;
            __builtin_amdgcn_global_load_lds(
                (const __attribute__((address_space(1))) void*)ga,
                (__attribute__((address_space(3))) void*)(As + e), 16, 0, 0);
            const unsigned short* gb = zn + (size_t)(cbase + row) * DIM + k0 + k;
            __builtin_amdgcn_global_load_lds(
                (const __attribute__((address_space(1))) void*)gb,
                (__attribute__((address_space(3))) void*)(Bs + e), 16, 0, 0);
        }
        __syncthreads();

#pragma unroll
        for (int kk = 0; kk < 2; ++kk) {
            const int kb = kk * 32 + (lane >> 4) * 8;
            bf16x8 a[4], b[4];
#pragma unroll
            for (int m = 0; m < 4; ++m)
                a[m] = *reinterpret_cast<const bf16x8*>(
                    &As[(wr * 64 + m * 16 + (lane & 15)) * BK + kb]);
#pragma unroll
            for (int n = 0; n < 4; ++n)
                b[n] = *reinterpret_cast<const bf16x8*>(
                    &Bs[(wc * 64 + n * 16 + (lane & 15)) * BK + kb]);
#pragma unroll
            for (int m = 0; m < 4; ++m)
#pragma unroll
                for (int n = 0; n < 4; ++n)
                    acc[m][n] = __builtin_amdgcn_mfma_f32_16x16x32_bf16(
                        a[m], b[n], acc[m][n], 0, 0, 0);
        }
        __syncthreads();
    }

    // ---- epilogue: per-row partial (max, sumexp) over this wave's 64 cols ----
    const float invT = 1.0f / 0.07f;
    const int c0 = cbase + wc * 64;
    const int chunk = ci * 2 + wc;
#pragma unroll
    for (int m = 0; m < 4; ++m) {
#pragma unroll
        for (int reg = 0; reg < 4; ++reg) {
            const int grow = rbase + wr * 64 + m * 16 + (lane >> 4) * 4 + reg;
            const int posj = (grow - 4096) & (N_ROWS - 1);
            float vals[4];
            float rmax = -3.4e38f;
#pragma unroll
            for (int n = 0; n < 4; ++n) {
                const int gcol = c0 + n * 16 + (lane & 15);
                float logit = acc[m][n][reg] * invT;
                if (gcol == grow) logit = -9e15f * invT;  // diag mask, matches reference
                if (gcol == posj) pos[grow] = logit;      // exactly one lane/block matches
                vals[n] = logit;
                rmax = fmaxf(rmax, logit);
            }
#pragma unroll
            for (int msk = 1; msk < 16; msk <<= 1)
                rmax = fmaxf(rmax, __shfl_xor(rmax, msk, 64));
            float s = 0.f;
#pragma unroll
            for (int n = 0; n < 4; ++n) s += __expf(vals[n] - rmax);
#pragma unroll
            for (int msk = 1; msk < 16; msk <<= 1) s += __shfl_xor(s, msk, 64);
            if ((lane & 15) == 0) {
                part[(size_t)chunk * N_ROWS + grow] = make_float2(rmax, s);
            }
        }
    }
}

// ---------------- Kernel 3: combine partials -> per-block nll sums ----------------
__global__ __launch_bounds__(256) void cl_combine_kernel(
    const float2* __restrict__ part, const float* __restrict__ pos,
    float* __restrict__ bsum) {
    const int r = blockIdx.x * 256 + threadIdx.x;
    float M = -3.4e38f;
#pragma unroll 8
    for (int c = 0; c < 128; ++c) M = fmaxf(M, part[(size_t)c * N_ROWS + r].x);
    float L = 0.f;
#pragma unroll 8
    for (int c = 0; c < 128; ++c) {
        const float2 p = part[(size_t)c * N_ROWS + r];
        L += p.y * __expf(p.x - M);
    }
    float nll = M + logf(L) - pos[r];
    __shared__ float red[4];
#pragma unroll
    for (int msk = 1; msk < 64; msk <<= 1) nll += __shfl_xor(nll, msk, 64);
    if ((threadIdx.x & 63) == 0) red[threadIdx.x >> 6] = nll;
    __syncthreads();
    if (threadIdx.x == 0) bsum[blockIdx.x] = red[0] + red[1] + red[2] + red[3];
}

// ---------------- Kernel 4: final mean ----------------
__global__ void cl_final_kernel(const float* __restrict__ bsum, float* __restrict__ out) {
    const int lane = threadIdx.x;
    float v = (lane < 32) ? bsum[lane] : 0.f;
#pragma unroll
    for (int msk = 1; msk < 64; msk <<= 1) v += __shfl_xor(v, msk, 64);
    if (lane == 0) out[0] = v * (1.0f / (float)N_ROWS);
}

extern "C" void kernel_launch(void* const* d_in, const int* in_sizes, int n_in,
                              void* d_out, int out_size, void* d_ws, size_t ws_size,
                              hipStream_t stream) {
    const float* z = (const float*)d_in[0];
    float* out = (float*)d_out;

    uint8_t* ws = (uint8_t*)d_ws;
    unsigned short* zn = (unsigned short*)ws;                       // 16 MB  (8192*1024*2)
    float2* part = (float2*)(ws + ((size_t)16 << 20));              //  8 MB  (128*8192*8)
    float* pos   = (float*)(ws + ((size_t)24 << 20));               // 32 KB
    float* bsum  = (float*)(ws + ((size_t)24 << 20) + 32768);       // 128 B

    cl_norm_kernel<<<N_ROWS / 4, 256, 0, stream>>>(z, zn);
    cl_simlse_kernel<<<dim3(N_ROWS / BN, N_ROWS / BM), 256, 0, stream>>>(zn, part, pos);
    cl_combine_kernel<<<N_ROWS / 256, 256, 0, stream>>>(part, pos, bsum);
    cl_final_kernel<<<1, 64, 0, stream>>>(bsum, out);
}

// Round 3
// 192.227 us; speedup vs baseline: 1.3800x; 1.3800x over previous
//
#include <hip/hip_runtime.h>
#include <hip/hip_bf16.h>
#include <math.h>

#define N_ROWS 8192
#define DIM 1024
#define BM 256
#define BN 256
#define BK 64
#define NT (DIM / BK)  // 16 K-tiles

typedef __attribute__((ext_vector_type(8))) __bf16 bf16x8;
typedef __attribute__((ext_vector_type(4))) float f32x4;

__device__ __forceinline__ unsigned short f2bf(float f) {
    unsigned u = __builtin_bit_cast(unsigned, f);
    u += 0x7fffu + ((u >> 16) & 1u);
    return (unsigned short)(u >> 16);
}

// ---------------- Kernel 1: row L2-normalize fp32 -> bf16 ----------------
__global__ __launch_bounds__(256) void cl_norm_kernel(
    const float* __restrict__ z, unsigned short* __restrict__ zn) {
    const int row  = blockIdx.x * 4 + (threadIdx.x >> 6);
    const int lane = threadIdx.x & 63;
    const float* zr = z + (size_t)row * DIM;
    float4 v[4];
    float ss = 0.f;
#pragma unroll
    for (int j = 0; j < 4; ++j) {
        v[j] = *reinterpret_cast<const float4*>(zr + j * 256 + lane * 4);
        ss += v[j].x * v[j].x + v[j].y * v[j].y + v[j].z * v[j].z + v[j].w * v[j].w;
    }
#pragma unroll
    for (int m = 1; m < 64; m <<= 1) ss += __shfl_xor(ss, m, 64);
    const float scale = 1.0f / fmaxf(sqrtf(ss), 1e-8f);
    unsigned short* zo = zn + (size_t)row * DIM;
#pragma unroll
    for (int j = 0; j < 4; ++j) {
        ushort4 o;
        o.x = f2bf(v[j].x * scale);
        o.y = f2bf(v[j].y * scale);
        o.z = f2bf(v[j].z * scale);
        o.w = f2bf(v[j].w * scale);
        *reinterpret_cast<ushort4*>(zo + j * 256 + lane * 4) = o;
    }
}

// ---------------- Kernel 2: 256x256 8-phase fused GEMM + partial LSE ----------------
// One "round" = 64 rows x 64 cols bf16 = 8 KB, staged by one global_load_lds
// per thread (512 thr x 16 B). LDS swizzle st_16 (XOR (row&7)<<4 on 16B chunks):
// write side pre-swizzles the GLOBAL source (linear LDS dest, rule #21),
// read side applies the same XOR.
__device__ __forceinline__ void stage_round(
    const unsigned short* __restrict__ zn, int g_row0, int k0,
    char* lds_round_base, int t) {
    const int r  = t >> 3;             // row within round (0..63)
    const int ch = (t & 7) ^ (r & 7);  // pre-swizzled 16B chunk
    const unsigned short* src = zn + (size_t)(g_row0 + r) * DIM + k0 + ch * 8;
    __builtin_amdgcn_global_load_lds(
        (const __attribute__((address_space(1))) void*)src,
        (__attribute__((address_space(3))) void*)(lds_round_base + t * 16), 16, 0, 0);
}

__device__ __forceinline__ bf16x8 ld_frag(const char* tile, int row, int kbyte, int xm) {
    return *reinterpret_cast<const bf16x8*>(tile + row * 128 + (kbyte ^ xm));
}

template <int MH, int NH>
__device__ __forceinline__ void mfma16(f32x4 (&acc)[8][4], const bf16x8 (&af)[4][2],
                                       const bf16x8 (&bfr)[2][2][2]) {
#pragma unroll
    for (int mi = 0; mi < 4; ++mi)
#pragma unroll
        for (int ni = 0; ni < 2; ++ni)
#pragma unroll
            for (int k = 0; k < 2; ++k)
                acc[MH * 4 + mi][NH * 2 + ni] = __builtin_amdgcn_mfma_f32_16x16x32_bf16(
                    af[mi][k], bfr[NH][ni][k], acc[MH * 4 + mi][NH * 2 + ni], 0, 0, 0);
}

__global__ __launch_bounds__(512, 2) void cl_simlse8_kernel(
    const unsigned short* __restrict__ zn,
    float2* __restrict__ part,  // [128 chunks][8192 rows]
    float* __restrict__ pos) {  // [8192]
    extern __shared__ char smem[];  // 2 bufs x (A 32KB + B 32KB) = 128 KB

    const int t    = threadIdx.x;
    const int lane = t & 63;
    const int wid  = t >> 6;   // 0..7
    const int wr   = wid >> 2; // 0..1 (M)
    const int wc   = wid & 3;  // 0..3 (N)
    const int l15  = lane & 15;
    const int xm   = (lane & 7) << 4;           // read-side swizzle mask
    const int kq16 = ((lane >> 4) & 3) * 16;    // k sub-chunk byte offset

    // XCD-aware swizzle: 1024 blocks, 1024 % 8 == 0 -> simple variant is bijective
    const int id  = blockIdx.x;
    const int swz = ((id & 7) << 7) | (id >> 3);
    const int ri  = swz >> 5;
    const int ci  = swz & 31;
    const int rbase = ri * BM;
    const int cbase = ci * BN;

    const f32x4 zero4 = {0.f, 0.f, 0.f, 0.f};
    f32x4 acc[8][4];
#pragma unroll
    for (int m = 0; m < 8; ++m)
#pragma unroll
        for (int n = 0; n < 4; ++n) acc[m][n] = zero4;

    bf16x8 af[4][2];      // current mh's A frags
    bf16x8 bfr[2][2][2];  // [nh][ni][k] B frags (both nh kept per K-tile)

    // ---------------- prologue: kt0 full (8 rounds) + kt1 A0+B (6 rounds) ----------------
    {
        char* A0 = smem;
        char* B0 = smem + 32768;
        char* A1 = smem + 65536;
        char* B1 = smem + 98304;
        stage_round(zn, rbase + 0,   0, A0 + 0,     t);
        stage_round(zn, rbase + 64,  0, A0 + 8192,  t);
        stage_round(zn, rbase + 128, 0, A0 + 16384, t);
        stage_round(zn, rbase + 192, 0, A0 + 24576, t);
        stage_round(zn, cbase + 0,   0, B0 + 0,     t);
        stage_round(zn, cbase + 64,  0, B0 + 8192,  t);
        stage_round(zn, cbase + 128, 0, B0 + 16384, t);
        stage_round(zn, cbase + 192, 0, B0 + 24576, t);
        stage_round(zn, rbase + 0,  BK, A1 + 0,     t);
        stage_round(zn, rbase + 64, BK, A1 + 8192,  t);
        stage_round(zn, cbase + 0,  BK, B1 + 0,     t);
        stage_round(zn, cbase + 64, BK, B1 + 8192,  t);
        stage_round(zn, cbase + 128,BK, B1 + 16384, t);
        stage_round(zn, cbase + 192,BK, B1 + 24576, t);
        asm volatile("s_waitcnt vmcnt(6)" ::: "memory");
        __builtin_amdgcn_sched_barrier(0);
        __builtin_amdgcn_s_barrier();
    }

    // ---------------- main loop: 4 phases per K-tile, counted vmcnt at boundaries ----------------
    for (int kt = 0; kt < NT; ++kt) {
        const int c = kt & 1;
        char* curA = smem + c * 65536;
        char* curB = curA + 32768;
        char* nxtA = smem + (c ^ 1) * 65536;

        // ---- phase 0: (mh0, nh0); read A-mh0 (8) + B-nh0 (4); stage (kt+1).A1 ----
#pragma unroll
        for (int mi = 0; mi < 4; ++mi)
#pragma unroll
            for (int k = 0; k < 2; ++k)
                af[mi][k] = ld_frag(curA, wr * 64 + mi * 16 + l15, k * 64 + kq16, xm);
#pragma unroll
        for (int ni = 0; ni < 2; ++ni)
#pragma unroll
            for (int k = 0; k < 2; ++k)
                bfr[0][ni][k] = ld_frag(curB, wc * 64 + ni * 16 + l15, k * 64 + kq16, xm);
        if (kt + 1 < NT) {
            stage_round(zn, rbase + 128, (kt + 1) * BK, nxtA + 16384, t);
            stage_round(zn, rbase + 192, (kt + 1) * BK, nxtA + 24576, t);
        }
        __builtin_amdgcn_s_barrier();
        asm volatile("s_waitcnt lgkmcnt(0)" ::: "memory");
        __builtin_amdgcn_sched_barrier(0);
        __builtin_amdgcn_s_setprio(1);
        mfma16<0, 0>(acc, af, bfr);
        __builtin_amdgcn_s_setprio(0);
        __builtin_amdgcn_s_barrier();

        // ---- phase 1: (mh0, nh1); read B-nh1 (4); stage (kt+2).A0 ----
#pragma unroll
        for (int ni = 0; ni < 2; ++ni)
#pragma unroll
            for (int k = 0; k < 2; ++k)
                bfr[1][ni][k] = ld_frag(curB, wc * 64 + 32 + ni * 16 + l15, k * 64 + kq16, xm);
        if (kt + 2 < NT) {
            stage_round(zn, rbase + 0,  (kt + 2) * BK, curA + 0,    t);
            stage_round(zn, rbase + 64, (kt + 2) * BK, curA + 8192, t);
        }
        __builtin_amdgcn_s_barrier();
        asm volatile("s_waitcnt lgkmcnt(0)" ::: "memory");
        __builtin_amdgcn_sched_barrier(0);
        __builtin_amdgcn_s_setprio(1);
        mfma16<0, 1>(acc, af, bfr);
        __builtin_amdgcn_s_setprio(0);
        __builtin_amdgcn_s_barrier();

        // ---- phase 2: (mh1, nh1); read A-mh1 (8); stage (kt+2).B rounds 0,1 ----
#pragma unroll
        for (int mi = 0; mi < 4; ++mi)
#pragma unroll
            for (int k = 0; k < 2; ++k)
                af[mi][k] = ld_frag(curA, wr * 64 + 128 + mi * 16 + l15, k * 64 + kq16, xm);
        if (kt + 2 < NT) {
            stage_round(zn, cbase + 0,  (kt + 2) * BK, curB + 0,    t);
            stage_round(zn, cbase + 64, (kt + 2) * BK, curB + 8192, t);
        }
        __builtin_amdgcn_s_barrier();
        asm volatile("s_waitcnt lgkmcnt(0)" ::: "memory");
        __builtin_amdgcn_sched_barrier(0);
        __builtin_amdgcn_s_setprio(1);
        mfma16<1, 1>(acc, af, bfr);
        __builtin_amdgcn_s_setprio(0);
        __builtin_amdgcn_s_barrier();

        // ---- phase 3: (mh1, nh0); no reads; stage (kt+2).B rounds 2,3; boundary vmcnt ----
        if (kt + 2 < NT) {
            stage_round(zn, cbase + 128, (kt + 2) * BK, curB + 16384, t);
            stage_round(zn, cbase + 192, (kt + 2) * BK, curB + 24576, t);
        }
        __builtin_amdgcn_s_setprio(1);
        mfma16<1, 0>(acc, af, bfr);
        __builtin_amdgcn_s_setprio(0);
        if (kt < NT - 1) {
            if (kt < NT - 2) {
                asm volatile("s_waitcnt vmcnt(6)" ::: "memory");
            } else {
                asm volatile("s_waitcnt vmcnt(0)" ::: "memory");
            }
            __builtin_amdgcn_sched_barrier(0);
            __builtin_amdgcn_s_barrier();
        }
    }

    // ---------------- epilogue: per-row partial (max, sumexp) over wave's 64 cols ----------------
    const float invT = 1.0f / 0.07f;
    const int chunk = ci * 4 + wc;
#pragma unroll
    for (int mh = 0; mh < 2; ++mh) {
#pragma unroll
        for (int mi = 0; mi < 4; ++mi) {
#pragma unroll
            for (int reg = 0; reg < 4; ++reg) {
                const int grow = rbase + wr * 64 + mh * 128 + mi * 16 + (lane >> 4) * 4 + reg;
                const int posj = (grow - 4096) & (N_ROWS - 1);
                float vals[4];
                float rmax = -3.4e38f;
#pragma unroll
                for (int nf = 0; nf < 4; ++nf) {
                    const int gcol = cbase + wc * 64 + (nf >> 1) * 32 + (nf & 1) * 16 + l15;
                    float logit = acc[mh * 4 + mi][nf][reg] * invT;
                    if (gcol == grow) logit = -9e15f * invT;  // diag mask
                    if (gcol == posj) pos[grow] = logit;
                    vals[nf] = logit;
                    rmax = fmaxf(rmax, logit);
                }
#pragma unroll
                for (int msk = 1; msk < 16; msk <<= 1)
                    rmax = fmaxf(rmax, __shfl_xor(rmax, msk, 64));
                float s = 0.f;
#pragma unroll
                for (int nf = 0; nf < 4; ++nf) s += __expf(vals[nf] - rmax);
#pragma unroll
                for (int msk = 1; msk < 16; msk <<= 1) s += __shfl_xor(s, msk, 64);
                if (l15 == 0) {
                    part[(size_t)chunk * N_ROWS + grow] = make_float2(rmax, s);
                }
            }
        }
    }
}

// ---------------- Kernel 3: combine partials -> per-block nll sums ----------------
__global__ __launch_bounds__(256) void cl_combine_kernel(
    const float2* __restrict__ part, const float* __restrict__ pos,
    float* __restrict__ bsum) {
    const int r = blockIdx.x * 256 + threadIdx.x;
    float M = -3.4e38f;
#pragma unroll 8
    for (int c = 0; c < 128; ++c) M = fmaxf(M, part[(size_t)c * N_ROWS + r].x);
    float L = 0.f;
#pragma unroll 8
    for (int c = 0; c < 128; ++c) {
        const float2 p = part[(size_t)c * N_ROWS + r];
        L += p.y * __expf(p.x - M);
    }
    float nll = M + logf(L) - pos[r];
    __shared__ float red[4];
#pragma unroll
    for (int msk = 1; msk < 64; msk <<= 1) nll += __shfl_xor(nll, msk, 64);
    if ((threadIdx.x & 63) == 0) red[threadIdx.x >> 6] = nll;
    __syncthreads();
    if (threadIdx.x == 0) bsum[blockIdx.x] = red[0] + red[1] + red[2] + red[3];
}

// ---------------- Kernel 4: final mean ----------------
__global__ void cl_final_kernel(const float* __restrict__ bsum, float* __restrict__ out) {
    const int lane = threadIdx.x;
    float v = (lane < 32) ? bsum[lane] : 0.f;
#pragma unroll
    for (int msk = 1; msk < 64; msk <<= 1) v += __shfl_xor(v, msk, 64);
    if (lane == 0) out[0] = v * (1.0f / (float)N_ROWS);
}

extern "C" void kernel_launch(void* const* d_in, const int* in_sizes, int n_in,
                              void* d_out, int out_size, void* d_ws, size_t ws_size,
                              hipStream_t stream) {
    const float* z = (const float*)d_in[0];
    float* out = (float*)d_out;

    uint8_t* ws = (uint8_t*)d_ws;
    unsigned short* zn = (unsigned short*)ws;                  // 16 MB
    float2* part = (float2*)(ws + ((size_t)16 << 20));         //  8 MB (128*8192*8)
    float* pos   = (float*)(ws + ((size_t)24 << 20));          // 32 KB
    float* bsum  = (float*)(ws + ((size_t)24 << 20) + 32768);  // 128 B

    (void)hipFuncSetAttribute((const void*)cl_simlse8_kernel,
                              hipFuncAttributeMaxDynamicSharedMemorySize, 131072);

    cl_norm_kernel<<<N_ROWS / 4, 256, 0, stream>>>(z, zn);
    cl_simlse8_kernel<<<(N_ROWS / BM) * (N_ROWS / BN), 512, 131072, stream>>>(zn, part, pos);
    cl_combine_kernel<<<N_ROWS / 256, 256, 0, stream>>>(part, pos, bsum);
    cl_final_kernel<<<1, 64, 0, stream>>>(bsum, out);
}

// Round 4
// 186.014 us; speedup vs baseline: 1.4261x; 1.0334x over previous
//
#include <hip/hip_runtime.h>
#include <hip/hip_bf16.h>
#include <math.h>

#define N_ROWS 8192
#define DIM 1024
#define BM 256
#define BN 256
#define BK 64
#define NT (DIM / BK)  // 16 K-tiles

typedef __attribute__((ext_vector_type(8))) __bf16 bf16x8;
typedef __attribute__((ext_vector_type(4))) float f32x4;

__device__ __forceinline__ unsigned short f2bf(float f) {
    unsigned u = __builtin_bit_cast(unsigned, f);
    u += 0x7fffu + ((u >> 16) & 1u);
    return (unsigned short)(u >> 16);
}

// ---------------- Kernel 1: row L2-normalize fp32 -> bf16 ----------------
__global__ __launch_bounds__(256) void cl_norm_kernel(
    const float* __restrict__ z, unsigned short* __restrict__ zn) {
    const int row  = blockIdx.x * 4 + (threadIdx.x >> 6);
    const int lane = threadIdx.x & 63;
    const float* zr = z + (size_t)row * DIM;
    float4 v[4];
    float ss = 0.f;
#pragma unroll
    for (int j = 0; j < 4; ++j) {
        v[j] = *reinterpret_cast<const float4*>(zr + j * 256 + lane * 4);
        ss += v[j].x * v[j].x + v[j].y * v[j].y + v[j].z * v[j].z + v[j].w * v[j].w;
    }
#pragma unroll
    for (int m = 1; m < 64; m <<= 1) ss += __shfl_xor(ss, m, 64);
    const float scale = 1.0f / fmaxf(sqrtf(ss), 1e-8f);
    unsigned short* zo = zn + (size_t)row * DIM;
#pragma unroll
    for (int j = 0; j < 4; ++j) {
        ushort4 o;
        o.x = f2bf(v[j].x * scale);
        o.y = f2bf(v[j].y * scale);
        o.z = f2bf(v[j].z * scale);
        o.w = f2bf(v[j].w * scale);
        *reinterpret_cast<ushort4*>(zo + j * 256 + lane * 4) = o;
    }
}

// ---------------- Kernel 2: 256x256 8-phase fused GEMM + partial LSE ----------------
// Round = 64 rows x 64 cols bf16 = 8 KB staged by 512 thr x 16 B global_load_lds.
// Swizzle: linear LDS dest + inverse-swizzled global source (rule #21); reads XOR
// the same (row&7)<<4 mask.
__device__ __forceinline__ void stage_round(
    const unsigned short* __restrict__ zn, int g_row0, int k0,
    char* lds_round_base, int t) {
    const int r  = t >> 3;             // row within round (0..63)
    const int ch = (t & 7) ^ (r & 7);  // pre-swizzled 16B chunk
    const unsigned short* src = zn + (size_t)(g_row0 + r) * DIM + k0 + ch * 8;
    __builtin_amdgcn_global_load_lds(
        (const __attribute__((address_space(1))) void*)src,
        (__attribute__((address_space(3))) void*)(lds_round_base + t * 16), 16, 0, 0);
}

__device__ __forceinline__ bf16x8 ld_frag(const char* tile, int row, int kbyte, int xm) {
    return *reinterpret_cast<const bf16x8*>(tile + row * 128 + (kbyte ^ xm));
}

// One C-quadrant: 4(mi) x 2(ni) x 2(k) = 16 MFMA
template <int MH, int NH>
__device__ __forceinline__ void mfma_quad(f32x4 (&acc)[8][4], const bf16x8 (&af)[4][2],
                                          const bf16x8 (&bf)[2][2]) {
#pragma unroll
    for (int mi = 0; mi < 4; ++mi)
#pragma unroll
        for (int ni = 0; ni < 2; ++ni)
#pragma unroll
            for (int k = 0; k < 2; ++k)
                acc[MH * 4 + mi][NH * 2 + ni] = __builtin_amdgcn_mfma_f32_16x16x32_bf16(
                    af[mi][k], bf[ni][k], acc[MH * 4 + mi][NH * 2 + ni], 0, 0, 0);
}

__global__ __launch_bounds__(512, 2) void cl_simlse8_kernel(
    const unsigned short* __restrict__ zn,
    float2* __restrict__ part,  // [128 chunks][8192 rows]
    float* __restrict__ pos) {  // [8192]
    extern __shared__ char smem[];  // 2 bufs x (A 32KB + B 32KB) = 128 KB

    const int t    = threadIdx.x;
    const int lane = t & 63;
    const int wid  = t >> 6;   // 0..7
    const int wr   = wid >> 2; // 0..1 (M)
    const int wc   = wid & 3;  // 0..3 (N)
    const int l15  = lane & 15;
    const int xm   = (lane & 7) << 4;        // read-side swizzle mask ((row&7)<<4)
    const int kq16 = ((lane >> 4) & 3) * 16; // k sub-chunk byte offset

    // XCD-aware mapping: 8 XCDs x 128 blocks; each XCD owns a 16ri x 8ci rect.
    // Concurrent 32 CUs cover 4ri x 8ci = 2MB A + 4MB B (vs 16.5MB strip before).
    const int id  = blockIdx.x;
    const int xcd = id & 7;
    const int j   = id >> 3;                      // 0..127
    const int ri  = (xcd >> 2) * 16 + (j >> 3);   // 0..31
    const int ci  = (xcd & 3) * 8 + (j & 7);      // 0..31
    const int rbase = ri * BM;
    const int cbase = ci * BN;

    const f32x4 zero4 = {0.f, 0.f, 0.f, 0.f};
    f32x4 acc[8][4];
#pragma unroll
    for (int m = 0; m < 8; ++m)
#pragma unroll
        for (int n = 0; n < 4; ++n) acc[m][n] = zero4;

    bf16x8 af0[4][2], af1[4][2];  // A mh0 / mh1 fragments
    bf16x8 bfr0[2][2], bfr1[2][2];// B nh0 / nh1 fragments

    // ---------------- prologue: stage kt0 (8 rounds) then kt1 (8 rounds) ----------------
    {
        char* A0b = smem;
        char* B0b = smem + 32768;
        char* A1b = smem + 65536;
        char* B1b = smem + 98304;
        stage_round(zn, rbase + 0,   0, A0b + 0,     t);
        stage_round(zn, rbase + 64,  0, A0b + 8192,  t);
        stage_round(zn, rbase + 128, 0, A0b + 16384, t);
        stage_round(zn, rbase + 192, 0, A0b + 24576, t);
        stage_round(zn, cbase + 0,   0, B0b + 0,     t);
        stage_round(zn, cbase + 64,  0, B0b + 8192,  t);
        stage_round(zn, cbase + 128, 0, B0b + 16384, t);
        stage_round(zn, cbase + 192, 0, B0b + 24576, t);
        stage_round(zn, rbase + 0,   BK, A1b + 0,     t);
        stage_round(zn, rbase + 64,  BK, A1b + 8192,  t);
        stage_round(zn, rbase + 128, BK, A1b + 16384, t);
        stage_round(zn, rbase + 192, BK, A1b + 24576, t);
        stage_round(zn, cbase + 0,   BK, B1b + 0,     t);
        stage_round(zn, cbase + 64,  BK, B1b + 8192,  t);
        stage_round(zn, cbase + 128, BK, B1b + 16384, t);
        stage_round(zn, cbase + 192, BK, B1b + 24576, t);
        asm volatile("s_waitcnt vmcnt(8)" ::: "memory");  // kt0 complete, kt1 in flight
        __builtin_amdgcn_sched_barrier(0);
        __builtin_amdgcn_s_barrier();
    }
    // preload B-nh0(kt0) into registers
#pragma unroll
    for (int ni = 0; ni < 2; ++ni)
#pragma unroll
        for (int k = 0; k < 2; ++k)
            bfr0[ni][k] = ld_frag(smem + 32768, wc * 64 + ni * 16 + l15, k * 64 + kq16, xm);

    // ---------------- main loop: 4 phases/K-tile, boundary {vmcnt(4);barrier} at ph2-end ----------------
    for (int kt = 0; kt < NT; ++kt) {
        const int c = kt & 1;
        char* curA = smem + c * 65536;
        char* curB = curA + 32768;
        char* nxtB = smem + (c ^ 1) * 65536 + 32768;
        const int k2 = (kt + 2) * BK;

        // ---- ph0: read A-mh0 (8); MFMA(mh0,nh0) ----
#pragma unroll
        for (int mi = 0; mi < 4; ++mi)
#pragma unroll
            for (int k = 0; k < 2; ++k)
                af0[mi][k] = ld_frag(curA, wr * 64 + mi * 16 + l15, k * 64 + kq16, xm);
        __builtin_amdgcn_s_barrier();
        asm volatile("s_waitcnt lgkmcnt(0)" ::: "memory");
        __builtin_amdgcn_sched_barrier(0);
        __builtin_amdgcn_s_setprio(1);
        mfma_quad<0, 0>(acc, af0, bfr0);
        __builtin_amdgcn_s_setprio(0);
        __builtin_amdgcn_s_barrier();

        // ---- ph1: read A-mh1 (8); stage A0(kt+2); MFMA(mh1,nh0) ----
#pragma unroll
        for (int mi = 0; mi < 4; ++mi)
#pragma unroll
            for (int k = 0; k < 2; ++k)
                af1[mi][k] = ld_frag(curA, 128 + wr * 64 + mi * 16 + l15, k * 64 + kq16, xm);
        if (kt + 2 < NT) {
            stage_round(zn, rbase + 0,  k2, curA + 0,    t);
            stage_round(zn, rbase + 64, k2, curA + 8192, t);
        }
        __builtin_amdgcn_s_barrier();
        asm volatile("s_waitcnt lgkmcnt(0)" ::: "memory");
        __builtin_amdgcn_sched_barrier(0);
        __builtin_amdgcn_s_setprio(1);
        mfma_quad<1, 0>(acc, af1, bfr0);
        __builtin_amdgcn_s_setprio(0);
        __builtin_amdgcn_s_barrier();

        // ---- ph2: read B-nh1 (4); stage A1(kt+2); MFMA(mh1,nh1); boundary vmcnt ----
#pragma unroll
        for (int ni = 0; ni < 2; ++ni)
#pragma unroll
            for (int k = 0; k < 2; ++k)
                bfr1[ni][k] = ld_frag(curB, wc * 64 + 32 + ni * 16 + l15, k * 64 + kq16, xm);
        if (kt + 2 < NT) {
            stage_round(zn, rbase + 128, k2, curA + 16384, t);
            stage_round(zn, rbase + 192, k2, curA + 24576, t);
        }
        __builtin_amdgcn_s_barrier();
        asm volatile("s_waitcnt lgkmcnt(0)" ::: "memory");
        __builtin_amdgcn_sched_barrier(0);
        __builtin_amdgcn_s_setprio(1);
        mfma_quad<1, 1>(acc, af1, bfr1);
        __builtin_amdgcn_s_setprio(0);
        if (kt < NT - 2) {
            asm volatile("s_waitcnt vmcnt(4)" ::: "memory");  // all (kt+1) landed
            __builtin_amdgcn_sched_barrier(0);
        } else if (kt == NT - 2) {
            asm volatile("s_waitcnt vmcnt(0)" ::: "memory");  // drain tail
            __builtin_amdgcn_sched_barrier(0);
        }
        __builtin_amdgcn_s_barrier();

        // ---- ph3: stage B(kt+2) x4; MFMA(mh0,nh1); read next-tile B-nh0 (4) ----
        if (kt + 2 < NT) {
            stage_round(zn, cbase + 0,   k2, curB + 0,     t);
            stage_round(zn, cbase + 64,  k2, curB + 8192,  t);
            stage_round(zn, cbase + 128, k2, curB + 16384, t);
            stage_round(zn, cbase + 192, k2, curB + 24576, t);
        }
        __builtin_amdgcn_s_setprio(1);
        mfma_quad<0, 1>(acc, af0, bfr1);
        __builtin_amdgcn_s_setprio(0);
        if (kt + 1 < NT) {
#pragma unroll
            for (int ni = 0; ni < 2; ++ni)
#pragma unroll
                for (int k = 0; k < 2; ++k)
                    bfr0[ni][k] = ld_frag(nxtB, wc * 64 + ni * 16 + l15, k * 64 + kq16, xm);
        }
        __builtin_amdgcn_s_barrier();
    }

    // ---------------- epilogue: per-row partial (max, sumexp) over wave's 64 cols ----------------
    const float invT = 1.0f / 0.07f;
    const int chunk = ci * 4 + wc;
#pragma unroll
    for (int mh = 0; mh < 2; ++mh) {
#pragma unroll
        for (int mi = 0; mi < 4; ++mi) {
#pragma unroll
            for (int reg = 0; reg < 4; ++reg) {
                const int grow = rbase + wr * 64 + mh * 128 + mi * 16 + (lane >> 4) * 4 + reg;
                const int posj = (grow - 4096) & (N_ROWS - 1);
                float vals[4];
                float rmax = -3.4e38f;
#pragma unroll
                for (int nf = 0; nf < 4; ++nf) {
                    const int gcol = cbase + wc * 64 + (nf >> 1) * 32 + (nf & 1) * 16 + l15;
                    float logit = acc[mh * 4 + mi][nf][reg] * invT;
                    if (gcol == grow) logit = -9e15f * invT;  // diag mask
                    if (gcol == posj) pos[grow] = logit;
                    vals[nf] = logit;
                    rmax = fmaxf(rmax, logit);
                }
#pragma unroll
                for (int msk = 1; msk < 16; msk <<= 1)
                    rmax = fmaxf(rmax, __shfl_xor(rmax, msk, 64));
                float s = 0.f;
#pragma unroll
                for (int nf = 0; nf < 4; ++nf) s += __expf(vals[nf] - rmax);
#pragma unroll
                for (int msk = 1; msk < 16; msk <<= 1) s += __shfl_xor(s, msk, 64);
                if (l15 == 0) {
                    part[(size_t)chunk * N_ROWS + grow] = make_float2(rmax, s);
                }
            }
        }
    }
}

// ---------------- Kernel 3: combine partials -> per-block nll sums ----------------
__global__ __launch_bounds__(256) void cl_combine_kernel(
    const float2* __restrict__ part, const float* __restrict__ pos,
    float* __restrict__ bsum) {
    const int r = blockIdx.x * 256 + threadIdx.x;
    float M = -3.4e38f;
#pragma unroll 8
    for (int c = 0; c < 128; ++c) M = fmaxf(M, part[(size_t)c * N_ROWS + r].x);
    float L = 0.f;
#pragma unroll 8
    for (int c = 0; c < 128; ++c) {
        const float2 p = part[(size_t)c * N_ROWS + r];
        L += p.y * __expf(p.x - M);
    }
    float nll = M + logf(L) - pos[r];
    __shared__ float red[4];
#pragma unroll
    for (int msk = 1; msk < 64; msk <<= 1) nll += __shfl_xor(nll, msk, 64);
    if ((threadIdx.x & 63) == 0) red[threadIdx.x >> 6] = nll;
    __syncthreads();
    if (threadIdx.x == 0) bsum[blockIdx.x] = red[0] + red[1] + red[2] + red[3];
}

// ---------------- Kernel 4: final mean ----------------
__global__ void cl_final_kernel(const float* __restrict__ bsum, float* __restrict__ out) {
    const int lane = threadIdx.x;
    float v = (lane < 32) ? bsum[lane] : 0.f;
#pragma unroll
    for (int msk = 1; msk < 64; msk <<= 1) v += __shfl_xor(v, msk, 64);
    if (lane == 0) out[0] = v * (1.0f / (float)N_ROWS);
}

extern "C" void kernel_launch(void* const* d_in, const int* in_sizes, int n_in,
                              void* d_out, int out_size, void* d_ws, size_t ws_size,
                              hipStream_t stream) {
    const float* z = (const float*)d_in[0];
    float* out = (float*)d_out;

    uint8_t* ws = (uint8_t*)d_ws;
    unsigned short* zn = (unsigned short*)ws;                  // 16 MB
    float2* part = (float2*)(ws + ((size_t)16 << 20));         //  8 MB (128*8192*8)
    float* pos   = (float*)(ws + ((size_t)24 << 20));          // 32 KB
    float* bsum  = (float*)(ws + ((size_t)24 << 20) + 32768);  // 128 B

    (void)hipFuncSetAttribute((const void*)cl_simlse8_kernel,
                              hipFuncAttributeMaxDynamicSharedMemorySize, 131072);

    cl_norm_kernel<<<N_ROWS / 4, 256, 0, stream>>>(z, zn);
    cl_simlse8_kernel<<<(N_ROWS / BM) * (N_ROWS / BN), 512, 131072, stream>>>(zn, part, pos);
    cl_combine_kernel<<<N_ROWS / 256, 256, 0, stream>>>(part, pos, bsum);
    cl_final_kernel<<<1, 64, 0, stream>>>(bsum, out);
}

// Round 5
// 156.684 us; speedup vs baseline: 1.6930x; 1.1872x over previous
//
#include <hip/hip_runtime.h>
#include <hip/hip_bf16.h>
#include <math.h>

#define N_ROWS 8192
#define DIM 1024
#define BM 256
#define BN 256
#define BK 64
#define NT (DIM / BK)  // 16 K-tiles

typedef __attribute__((ext_vector_type(8))) __bf16 bf16x8;
typedef __attribute__((ext_vector_type(4))) float f32x4;

__device__ __forceinline__ unsigned short f2bf(float f) {
    unsigned u = __builtin_bit_cast(unsigned, f);
    u += 0x7fffu + ((u >> 16) & 1u);
    return (unsigned short)(u >> 16);
}

// ---------------- Kernel 1: row L2-normalize fp32 -> bf16 ----------------
__global__ __launch_bounds__(256) void cl_norm_kernel(
    const float* __restrict__ z, unsigned short* __restrict__ zn) {
    const int row  = blockIdx.x * 4 + (threadIdx.x >> 6);
    const int lane = threadIdx.x & 63;
    const float* zr = z + (size_t)row * DIM;
    float4 v[4];
    float ss = 0.f;
#pragma unroll
    for (int j = 0; j < 4; ++j) {
        v[j] = *reinterpret_cast<const float4*>(zr + j * 256 + lane * 4);
        ss += v[j].x * v[j].x + v[j].y * v[j].y + v[j].z * v[j].z + v[j].w * v[j].w;
    }
#pragma unroll
    for (int m = 1; m < 64; m <<= 1) ss += __shfl_xor(ss, m, 64);
    const float scale = 1.0f / fmaxf(sqrtf(ss), 1e-8f);
    unsigned short* zo = zn + (size_t)row * DIM;
#pragma unroll
    for (int j = 0; j < 4; ++j) {
        ushort4 o;
        o.x = f2bf(v[j].x * scale);
        o.y = f2bf(v[j].y * scale);
        o.z = f2bf(v[j].z * scale);
        o.w = f2bf(v[j].w * scale);
        *reinterpret_cast<ushort4*>(zo + j * 256 + lane * 4) = o;
    }
}

// ---------------- Kernel 2: symmetric 256x256 8-phase GEMM + dual partial LSE ----------------
// Only upper-triangle tiles (ri<=ci) are computed: 528 blocks. Off-diagonal
// blocks emit BOTH row-wise partials (rows of ri-tile over ci's cols) and
// column-wise partials (= transpose rows: rows of ci-tile over ri's cols).
// Coverage of part[chunk][row] is exact and unique -> combine unchanged.
__device__ __forceinline__ void stage_round(
    const unsigned short* __restrict__ zn, int g_row0, int k0,
    char* lds_round_base, int t) {
    const int r  = t >> 3;             // row within round (0..63)
    const int ch = (t & 7) ^ (r & 7);  // pre-swizzled 16B chunk (rule #21: swizzle source)
    const unsigned short* src = zn + (size_t)(g_row0 + r) * DIM + k0 + ch * 8;
    __builtin_amdgcn_global_load_lds(
        (const __attribute__((address_space(1))) void*)src,
        (__attribute__((address_space(3))) void*)(lds_round_base + t * 16), 16, 0, 0);
}

__device__ __forceinline__ bf16x8 ld_frag(const char* tile, int row, int kbyte, int xm) {
    return *reinterpret_cast<const bf16x8*>(tile + row * 128 + (kbyte ^ xm));
}

template <int MH, int NH>
__device__ __forceinline__ void mfma_quad(f32x4 (&acc)[8][4], const bf16x8 (&af)[4][2],
                                          const bf16x8 (&bf)[2][2]) {
#pragma unroll
    for (int mi = 0; mi < 4; ++mi)
#pragma unroll
        for (int ni = 0; ni < 2; ++ni)
#pragma unroll
            for (int k = 0; k < 2; ++k)
                acc[MH * 4 + mi][NH * 2 + ni] = __builtin_amdgcn_mfma_f32_16x16x32_bf16(
                    af[mi][k], bf[ni][k], acc[MH * 4 + mi][NH * 2 + ni], 0, 0, 0);
}

__global__ __launch_bounds__(512, 2) void cl_simlse8_kernel(
    const unsigned short* __restrict__ zn,
    float2* __restrict__ part,  // [128 chunks][8192 rows]
    float* __restrict__ pos) {  // [8192]
    extern __shared__ char smem[];  // 2 bufs x (A 32KB + B 32KB) = 128 KB

    const int t    = threadIdx.x;
    const int lane = t & 63;
    const int wid  = t >> 6;   // 0..7
    const int wr   = wid >> 2; // 0..1 (M)
    const int wc   = wid & 3;  // 0..3 (N)
    const int l15  = lane & 15;
    const int xm   = (lane & 7) << 4;        // read-side swizzle mask ((row&7)<<4)
    const int kq16 = ((lane >> 4) & 3) * 16; // k sub-chunk byte offset

    // 528 upper-triangle tiles; 528 = 8 * 66 -> chunked XCD mapping (bijective).
    const int id2 = (blockIdx.x & 7) * 66 + (blockIdx.x >> 3);
    int ri = 0, rem = id2;
    while (rem >= 32 - ri) { rem -= 32 - ri; ++ri; }
    const int ci = ri + rem;  // ri <= ci
    const int rbase = ri * BM;
    const int cbase = ci * BN;

    const f32x4 zero4 = {0.f, 0.f, 0.f, 0.f};
    f32x4 acc[8][4];
#pragma unroll
    for (int m = 0; m < 8; ++m)
#pragma unroll
        for (int n = 0; n < 4; ++n) acc[m][n] = zero4;

    bf16x8 af0[4][2], af1[4][2];   // A mh0 / mh1 fragments
    bf16x8 bfr0[2][2], bfr1[2][2]; // B nh0 / nh1 fragments

    // ---------------- prologue: stage kt0 (8 rounds) then kt1 (8 rounds) ----------------
    {
        char* A0b = smem;
        char* B0b = smem + 32768;
        char* A1b = smem + 65536;
        char* B1b = smem + 98304;
        stage_round(zn, rbase + 0,   0, A0b + 0,     t);
        stage_round(zn, rbase + 64,  0, A0b + 8192,  t);
        stage_round(zn, rbase + 128, 0, A0b + 16384, t);
        stage_round(zn, rbase + 192, 0, A0b + 24576, t);
        stage_round(zn, cbase + 0,   0, B0b + 0,     t);
        stage_round(zn, cbase + 64,  0, B0b + 8192,  t);
        stage_round(zn, cbase + 128, 0, B0b + 16384, t);
        stage_round(zn, cbase + 192, 0, B0b + 24576, t);
        stage_round(zn, rbase + 0,   BK, A1b + 0,     t);
        stage_round(zn, rbase + 64,  BK, A1b + 8192,  t);
        stage_round(zn, rbase + 128, BK, A1b + 16384, t);
        stage_round(zn, rbase + 192, BK, A1b + 24576, t);
        stage_round(zn, cbase + 0,   BK, B1b + 0,     t);
        stage_round(zn, cbase + 64,  BK, B1b + 8192,  t);
        stage_round(zn, cbase + 128, BK, B1b + 16384, t);
        stage_round(zn, cbase + 192, BK, B1b + 24576, t);
        asm volatile("s_waitcnt vmcnt(8)" ::: "memory");  // kt0 complete, kt1 in flight
        __builtin_amdgcn_sched_barrier(0);
        __builtin_amdgcn_s_barrier();
    }
    // preload B-nh0(kt0) into registers
#pragma unroll
    for (int ni = 0; ni < 2; ++ni)
#pragma unroll
        for (int k = 0; k < 2; ++k)
            bfr0[ni][k] = ld_frag(smem + 32768, wc * 64 + ni * 16 + l15, k * 64 + kq16, xm);

    // ---------------- main loop: 4 phases/K-tile, boundary {vmcnt;barrier} at ph2-end ----------------
    for (int kt = 0; kt < NT; ++kt) {
        const int c = kt & 1;
        char* curA = smem + c * 65536;
        char* curB = curA + 32768;
        char* nxtB = smem + (c ^ 1) * 65536 + 32768;
        const int k2 = (kt + 2) * BK;

        // ---- ph0: read A-mh0 (8); MFMA(mh0,nh0) ----
#pragma unroll
        for (int mi = 0; mi < 4; ++mi)
#pragma unroll
            for (int k = 0; k < 2; ++k)
                af0[mi][k] = ld_frag(curA, wr * 64 + mi * 16 + l15, k * 64 + kq16, xm);
        __builtin_amdgcn_s_barrier();
        asm volatile("s_waitcnt lgkmcnt(0)" ::: "memory");
        __builtin_amdgcn_sched_barrier(0);
        __builtin_amdgcn_s_setprio(1);
        mfma_quad<0, 0>(acc, af0, bfr0);
        __builtin_amdgcn_s_setprio(0);
        __builtin_amdgcn_s_barrier();

        // ---- ph1: read A-mh1 (8); stage A0(kt+2); MFMA(mh1,nh0) ----
#pragma unroll
        for (int mi = 0; mi < 4; ++mi)
#pragma unroll
            for (int k = 0; k < 2; ++k)
                af1[mi][k] = ld_frag(curA, 128 + wr * 64 + mi * 16 + l15, k * 64 + kq16, xm);
        if (kt + 2 < NT) {
            stage_round(zn, rbase + 0,  k2, curA + 0,    t);
            stage_round(zn, rbase + 64, k2, curA + 8192, t);
        }
        __builtin_amdgcn_s_barrier();
        asm volatile("s_waitcnt lgkmcnt(0)" ::: "memory");
        __builtin_amdgcn_sched_barrier(0);
        __builtin_amdgcn_s_setprio(1);
        mfma_quad<1, 0>(acc, af1, bfr0);
        __builtin_amdgcn_s_setprio(0);
        __builtin_amdgcn_s_barrier();

        // ---- ph2: read B-nh1 (4); stage A1(kt+2); MFMA(mh1,nh1); boundary vmcnt ----
#pragma unroll
        for (int ni = 0; ni < 2; ++ni)
#pragma unroll
            for (int k = 0; k < 2; ++k)
                bfr1[ni][k] = ld_frag(curB, wc * 64 + 32 + ni * 16 + l15, k * 64 + kq16, xm);
        if (kt + 2 < NT) {
            stage_round(zn, rbase + 128, k2, curA + 16384, t);
            stage_round(zn, rbase + 192, k2, curA + 24576, t);
        }
        __builtin_amdgcn_s_barrier();
        asm volatile("s_waitcnt lgkmcnt(0)" ::: "memory");
        __builtin_amdgcn_sched_barrier(0);
        __builtin_amdgcn_s_setprio(1);
        mfma_quad<1, 1>(acc, af1, bfr1);
        __builtin_amdgcn_s_setprio(0);
        if (kt < NT - 2) {
            asm volatile("s_waitcnt vmcnt(4)" ::: "memory");  // all (kt+1) landed
            __builtin_amdgcn_sched_barrier(0);
        } else if (kt == NT - 2) {
            asm volatile("s_waitcnt vmcnt(0)" ::: "memory");  // drain tail
            __builtin_amdgcn_sched_barrier(0);
        }
        __builtin_amdgcn_s_barrier();

        // ---- ph3: stage B(kt+2) x4; MFMA(mh0,nh1); read next-tile B-nh0 (4) ----
        if (kt + 2 < NT) {
            stage_round(zn, cbase + 0,   k2, curB + 0,     t);
            stage_round(zn, cbase + 64,  k2, curB + 8192,  t);
            stage_round(zn, cbase + 128, k2, curB + 16384, t);
            stage_round(zn, cbase + 192, k2, curB + 24576, t);
        }
        __builtin_amdgcn_s_setprio(1);
        mfma_quad<0, 1>(acc, af0, bfr1);
        __builtin_amdgcn_s_setprio(0);
        if (kt + 1 < NT) {
#pragma unroll
            for (int ni = 0; ni < 2; ++ni)
#pragma unroll
                for (int k = 0; k < 2; ++k)
                    bfr0[ni][k] = ld_frag(nxtB, wc * 64 + ni * 16 + l15, k * 64 + kq16, xm);
        }
        __builtin_amdgcn_s_barrier();
    }

    const float invT = 1.0f / 0.07f;

    // ---------------- epilogue A: row partials (rows of ri-tile over ci's cols) ----------------
    const int chunk = ci * 4 + wc;
#pragma unroll
    for (int mh = 0; mh < 2; ++mh) {
#pragma unroll
        for (int mi = 0; mi < 4; ++mi) {
#pragma unroll
            for (int reg = 0; reg < 4; ++reg) {
                const int grow = rbase + wr * 64 + mh * 128 + mi * 16 + (lane >> 4) * 4 + reg;
                const int posj = (grow - 4096) & (N_ROWS - 1);
                float vals[4];
                float rmax = -3.4e38f;
#pragma unroll
                for (int nf = 0; nf < 4; ++nf) {
                    const int gcol = cbase + wc * 64 + (nf >> 1) * 32 + (nf & 1) * 16 + l15;
                    float logit = acc[mh * 4 + mi][nf][reg] * invT;
                    if (gcol == grow) logit = -9e15f * invT;  // diag mask (diag tiles only)
                    if (gcol == posj) {
                        pos[grow] = logit;   // (grow, gcol) pair; N/2 shift is an involution:
                        pos[gcol] = logit;   // sim symmetric -> pos[gcol] is the same value
                    }
                    vals[nf] = logit;
                    rmax = fmaxf(rmax, logit);
                }
#pragma unroll
                for (int msk = 1; msk < 16; msk <<= 1)
                    rmax = fmaxf(rmax, __shfl_xor(rmax, msk, 64));
                float s = 0.f;
#pragma unroll
                for (int nf = 0; nf < 4; ++nf) s += __expf(vals[nf] - rmax);
#pragma unroll
                for (int msk = 1; msk < 16; msk <<= 1) s += __shfl_xor(s, msk, 64);
                if (l15 == 0) {
                    part[(size_t)chunk * N_ROWS + grow] = make_float2(rmax, s);
                }
            }
        }
    }

    // ---------------- epilogue B: column partials (transpose rows) — off-diag only ----------------
    if (ri != ci) {
        // Per column gcol, LSE over this wave's 64 rows (rbase + wr*64 + mh*128 + [0,64)).
        // chunkT = that row-range / 64. Lane holds 16 vals (mi,reg); cross-lane over lane>>4.
#pragma unroll
        for (int mh = 0; mh < 2; ++mh) {
            const int chunkT = ri * 4 + wr + mh * 2;
#pragma unroll
            for (int nf = 0; nf < 4; ++nf) {
                const int gcol = cbase + wc * 64 + (nf >> 1) * 32 + (nf & 1) * 16 + l15;
                float cmax = -3.4e38f;
#pragma unroll
                for (int mi = 0; mi < 4; ++mi)
#pragma unroll
                    for (int reg = 0; reg < 4; ++reg)
                        cmax = fmaxf(cmax, acc[mh * 4 + mi][nf][reg] * invT);
                cmax = fmaxf(cmax, __shfl_xor(cmax, 16, 64));
                cmax = fmaxf(cmax, __shfl_xor(cmax, 32, 64));
                float cs = 0.f;
#pragma unroll
                for (int mi = 0; mi < 4; ++mi)
#pragma unroll
                    for (int reg = 0; reg < 4; ++reg)
                        cs += __expf(acc[mh * 4 + mi][nf][reg] * invT - cmax);
                cs += __shfl_xor(cs, 16, 64);
                cs += __shfl_xor(cs, 32, 64);
                if (lane < 16) {
                    part[(size_t)chunkT * N_ROWS + gcol] = make_float2(cmax, cs);
                }
            }
        }
    }
}

// ---------------- Kernel 3: combine partials -> per-block nll sums ----------------
__global__ __launch_bounds__(256) void cl_combine_kernel(
    const float2* __restrict__ part, const float* __restrict__ pos,
    float* __restrict__ bsum) {
    const int r = blockIdx.x * 256 + threadIdx.x;
    float M = -3.4e38f;
#pragma unroll 8
    for (int c = 0; c < 128; ++c) M = fmaxf(M, part[(size_t)c * N_ROWS + r].x);
    float L = 0.f;
#pragma unroll 8
    for (int c = 0; c < 128; ++c) {
        const float2 p = part[(size_t)c * N_ROWS + r];
        L += p.y * __expf(p.x - M);
    }
    float nll = M + logf(L) - pos[r];
    __shared__ float red[4];
#pragma unroll
    for (int msk = 1; msk < 64; msk <<= 1) nll += __shfl_xor(nll, msk, 64);
    if ((threadIdx.x & 63) == 0) red[threadIdx.x >> 6] = nll;
    __syncthreads();
    if (threadIdx.x == 0) bsum[blockIdx.x] = red[0] + red[1] + red[2] + red[3];
}

// ---------------- Kernel 4: final mean ----------------
__global__ void cl_final_kernel(const float* __restrict__ bsum, float* __restrict__ out) {
    const int lane = threadIdx.x;
    float v = (lane < 32) ? bsum[lane] : 0.f;
#pragma unroll
    for (int msk = 1; msk < 64; msk <<= 1) v += __shfl_xor(v, msk, 64);
    if (lane == 0) out[0] = v * (1.0f / (float)N_ROWS);
}

extern "C" void kernel_launch(void* const* d_in, const int* in_sizes, int n_in,
                              void* d_out, int out_size, void* d_ws, size_t ws_size,
                              hipStream_t stream) {
    const float* z = (const float*)d_in[0];
    float* out = (float*)d_out;

    uint8_t* ws = (uint8_t*)d_ws;
    unsigned short* zn = (unsigned short*)ws;                  // 16 MB
    float2* part = (float2*)(ws + ((size_t)16 << 20));         //  8 MB (128*8192*8)
    float* pos   = (float*)(ws + ((size_t)24 << 20));          // 32 KB
    float* bsum  = (float*)(ws + ((size_t)24 << 20) + 32768);  // 128 B

    (void)hipFuncSetAttribute((const void*)cl_simlse8_kernel,
                              hipFuncAttributeMaxDynamicSharedMemorySize, 131072);

    cl_norm_kernel<<<N_ROWS / 4, 256, 0, stream>>>(z, zn);
    cl_simlse8_kernel<<<528, 512, 131072, stream>>>(zn, part, pos);  // upper triangle
    cl_combine_kernel<<<N_ROWS / 256, 256, 0, stream>>>(part, pos, bsum);
    cl_final_kernel<<<1, 64, 0, stream>>>(bsum, out);
}

// Round 6
// 139.029 us; speedup vs baseline: 1.9080x; 1.1270x over previous
//
#include <hip/hip_runtime.h>
#include <hip/hip_bf16.h>
#include <math.h>

#define N_ROWS 8192
#define DIM 1024
#define BM 256
#define BN 256
#define BK 64
#define NT (DIM / BK)  // 16 K-tiles

typedef __attribute__((ext_vector_type(8))) __bf16 bf16x8;
typedef __attribute__((ext_vector_type(4))) float f32x4;

__device__ __forceinline__ unsigned short f2bf(float f) {
    unsigned u = __builtin_bit_cast(unsigned, f);
    u += 0x7fffu + ((u >> 16) & 1u);
    return (unsigned short)(u >> 16);
}

// ---------------- Kernel 1: row L2-normalize fp32 -> bf16 ----------------
__global__ __launch_bounds__(256) void cl_norm_kernel(
    const float* __restrict__ z, unsigned short* __restrict__ zn) {
    const int row  = blockIdx.x * 4 + (threadIdx.x >> 6);
    const int lane = threadIdx.x & 63;
    const float* zr = z + (size_t)row * DIM;
    float4 v[4];
    float ss = 0.f;
#pragma unroll
    for (int j = 0; j < 4; ++j) {
        v[j] = *reinterpret_cast<const float4*>(zr + j * 256 + lane * 4);
        ss += v[j].x * v[j].x + v[j].y * v[j].y + v[j].z * v[j].z + v[j].w * v[j].w;
    }
#pragma unroll
    for (int m = 1; m < 64; m <<= 1) ss += __shfl_xor(ss, m, 64);
    const float scale = 1.0f / fmaxf(sqrtf(ss), 1e-8f);
    unsigned short* zo = zn + (size_t)row * DIM;
#pragma unroll
    for (int j = 0; j < 4; ++j) {
        ushort4 o;
        o.x = f2bf(v[j].x * scale);
        o.y = f2bf(v[j].y * scale);
        o.z = f2bf(v[j].z * scale);
        o.w = f2bf(v[j].w * scale);
        *reinterpret_cast<ushort4*>(zo + j * 256 + lane * 4) = o;
    }
}

// ---------------- Kernel 2: symmetric triangle GEMM + dual partial LSE ----------------
// 528 upper-triangle tiles = 512 full 256x256 blocks (ids 0..511) + the last 16
// tiles split column-wise into 64 strips of 256x64 (ids 512..575) to kill the
// 1-block/CU scheduling quantization tail (528 = 2x256 + 16 -> full extra round).
__device__ __forceinline__ void stage_round(
    const unsigned short* __restrict__ zn, int g_row0, int k0,
    char* lds_round_base, int t) {
    const int r  = t >> 3;             // row within round (0..63)
    const int ch = (t & 7) ^ (r & 7);  // pre-swizzled 16B chunk (rule #21: swizzle source)
    const unsigned short* src = zn + (size_t)(g_row0 + r) * DIM + k0 + ch * 8;
    __builtin_amdgcn_global_load_lds(
        (const __attribute__((address_space(1))) void*)src,
        (__attribute__((address_space(3))) void*)(lds_round_base + t * 16), 16, 0, 0);
}

__device__ __forceinline__ bf16x8 ld_frag(const char* tile, int row, int kbyte, int xm) {
    return *reinterpret_cast<const bf16x8*>(tile + row * 128 + (kbyte ^ xm));
}

template <int MH, int NH>
__device__ __forceinline__ void mfma_quad(f32x4 (&acc)[8][4], const bf16x8 (&af)[4][2],
                                          const bf16x8 (&bf)[2][2]) {
#pragma unroll
    for (int mi = 0; mi < 4; ++mi)
#pragma unroll
        for (int ni = 0; ni < 2; ++ni)
#pragma unroll
            for (int k = 0; k < 2; ++k)
                acc[MH * 4 + mi][NH * 2 + ni] = __builtin_amdgcn_mfma_f32_16x16x32_bf16(
                    af[mi][k], bf[ni][k], acc[MH * 4 + mi][NH * 2 + ni], 0, 0, 0);
}

__global__ __launch_bounds__(512, 2) void cl_simlse8_kernel(
    const unsigned short* __restrict__ zn,
    float2* __restrict__ part,  // [128 chunks][8192 rows]
    float* __restrict__ pos) {  // [8192]
    extern __shared__ char smem[];  // 128 KB allocated

    const int t    = threadIdx.x;
    const int lane = t & 63;
    const int wid  = t >> 6;   // 0..7
    const int l15  = lane & 15;
    const int xm   = (lane & 7) << 4;        // read-side swizzle mask ((row&7)<<4)
    const int kq16 = ((lane >> 4) & 3) * 16; // k sub-chunk byte offset
    const float invT = 1.0f / 0.07f;

    if (blockIdx.x < 512) {
        // ================= FULL 256x256 tile path (triangle ids 0..511) =================
        const int wr = wid >> 2;  // 0..1 (M)
        const int wc = wid & 3;   // 0..3 (N)
        const int id2 = (blockIdx.x & 7) * 64 + (blockIdx.x >> 3);  // bijective XCD chunking
        int ri = 0, rem = id2;
        while (rem >= 32 - ri) { rem -= 32 - ri; ++ri; }
        const int ci = ri + rem;  // ri <= ci
        const int rbase = ri * BM;
        const int cbase = ci * BN;

        const f32x4 zero4 = {0.f, 0.f, 0.f, 0.f};
        f32x4 acc[8][4];
#pragma unroll
        for (int m = 0; m < 8; ++m)
#pragma unroll
            for (int n = 0; n < 4; ++n) acc[m][n] = zero4;

        bf16x8 af0[4][2], af1[4][2];
        bf16x8 bfr0[2][2], bfr1[2][2];

        // ---- prologue: stage kt0 (8 rounds) then kt1 (8 rounds) ----
        {
            char* A0b = smem;
            char* B0b = smem + 32768;
            char* A1b = smem + 65536;
            char* B1b = smem + 98304;
            stage_round(zn, rbase + 0,   0, A0b + 0,     t);
            stage_round(zn, rbase + 64,  0, A0b + 8192,  t);
            stage_round(zn, rbase + 128, 0, A0b + 16384, t);
            stage_round(zn, rbase + 192, 0, A0b + 24576, t);
            stage_round(zn, cbase + 0,   0, B0b + 0,     t);
            stage_round(zn, cbase + 64,  0, B0b + 8192,  t);
            stage_round(zn, cbase + 128, 0, B0b + 16384, t);
            stage_round(zn, cbase + 192, 0, B0b + 24576, t);
            stage_round(zn, rbase + 0,   BK, A1b + 0,     t);
            stage_round(zn, rbase + 64,  BK, A1b + 8192,  t);
            stage_round(zn, rbase + 128, BK, A1b + 16384, t);
            stage_round(zn, rbase + 192, BK, A1b + 24576, t);
            stage_round(zn, cbase + 0,   BK, B1b + 0,     t);
            stage_round(zn, cbase + 64,  BK, B1b + 8192,  t);
            stage_round(zn, cbase + 128, BK, B1b + 16384, t);
            stage_round(zn, cbase + 192, BK, B1b + 24576, t);
            asm volatile("s_waitcnt vmcnt(8)" ::: "memory");  // kt0 complete, kt1 in flight
            __builtin_amdgcn_sched_barrier(0);
            __builtin_amdgcn_s_barrier();
        }
#pragma unroll
        for (int ni = 0; ni < 2; ++ni)
#pragma unroll
            for (int k = 0; k < 2; ++k)
                bfr0[ni][k] = ld_frag(smem + 32768, wc * 64 + ni * 16 + l15, k * 64 + kq16, xm);

        // ---- main loop: 4 phases/K-tile, boundary {vmcnt;barrier} at ph2-end ----
        for (int kt = 0; kt < NT; ++kt) {
            const int c = kt & 1;
            char* curA = smem + c * 65536;
            char* curB = curA + 32768;
            char* nxtB = smem + (c ^ 1) * 65536 + 32768;
            const int k2 = (kt + 2) * BK;

            // ph0: read A-mh0 (8); MFMA(mh0,nh0)
#pragma unroll
            for (int mi = 0; mi < 4; ++mi)
#pragma unroll
                for (int k = 0; k < 2; ++k)
                    af0[mi][k] = ld_frag(curA, wr * 64 + mi * 16 + l15, k * 64 + kq16, xm);
            __builtin_amdgcn_s_barrier();
            asm volatile("s_waitcnt lgkmcnt(0)" ::: "memory");
            __builtin_amdgcn_sched_barrier(0);
            __builtin_amdgcn_s_setprio(1);
            mfma_quad<0, 0>(acc, af0, bfr0);
            __builtin_amdgcn_s_setprio(0);
            __builtin_amdgcn_s_barrier();

            // ph1: read A-mh1 (8); stage A0(kt+2); MFMA(mh1,nh0)
#pragma unroll
            for (int mi = 0; mi < 4; ++mi)
#pragma unroll
                for (int k = 0; k < 2; ++k)
                    af1[mi][k] = ld_frag(curA, 128 + wr * 64 + mi * 16 + l15, k * 64 + kq16, xm);
            if (kt + 2 < NT) {
                stage_round(zn, rbase + 0,  k2, curA + 0,    t);
                stage_round(zn, rbase + 64, k2, curA + 8192, t);
            }
            __builtin_amdgcn_s_barrier();
            asm volatile("s_waitcnt lgkmcnt(0)" ::: "memory");
            __builtin_amdgcn_sched_barrier(0);
            __builtin_amdgcn_s_setprio(1);
            mfma_quad<1, 0>(acc, af1, bfr0);
            __builtin_amdgcn_s_setprio(0);
            __builtin_amdgcn_s_barrier();

            // ph2: read B-nh1 (4); stage A1(kt+2); MFMA(mh1,nh1); boundary vmcnt
#pragma unroll
            for (int ni = 0; ni < 2; ++ni)
#pragma unroll
                for (int k = 0; k < 2; ++k)
                    bfr1[ni][k] = ld_frag(curB, wc * 64 + 32 + ni * 16 + l15, k * 64 + kq16, xm);
            if (kt + 2 < NT) {
                stage_round(zn, rbase + 128, k2, curA + 16384, t);
                stage_round(zn, rbase + 192, k2, curA + 24576, t);
            }
            __builtin_amdgcn_s_barrier();
            asm volatile("s_waitcnt lgkmcnt(0)" ::: "memory");
            __builtin_amdgcn_sched_barrier(0);
            __builtin_amdgcn_s_setprio(1);
            mfma_quad<1, 1>(acc, af1, bfr1);
            __builtin_amdgcn_s_setprio(0);
            if (kt < NT - 2) {
                asm volatile("s_waitcnt vmcnt(4)" ::: "memory");  // all (kt+1) landed
                __builtin_amdgcn_sched_barrier(0);
            } else if (kt == NT - 2) {
                asm volatile("s_waitcnt vmcnt(0)" ::: "memory");  // drain tail
                __builtin_amdgcn_sched_barrier(0);
            }
            __builtin_amdgcn_s_barrier();

            // ph3: stage B(kt+2) x4; MFMA(mh0,nh1); read next-tile B-nh0 (4)
            if (kt + 2 < NT) {
                stage_round(zn, cbase + 0,   k2, curB + 0,     t);
                stage_round(zn, cbase + 64,  k2, curB + 8192,  t);
                stage_round(zn, cbase + 128, k2, curB + 16384, t);
                stage_round(zn, cbase + 192, k2, curB + 24576, t);
            }
            __builtin_amdgcn_s_setprio(1);
            mfma_quad<0, 1>(acc, af0, bfr1);
            __builtin_amdgcn_s_setprio(0);
            if (kt + 1 < NT) {
#pragma unroll
                for (int ni = 0; ni < 2; ++ni)
#pragma unroll
                    for (int k = 0; k < 2; ++k)
                        bfr0[ni][k] = ld_frag(nxtB, wc * 64 + ni * 16 + l15, k * 64 + kq16, xm);
            }
            __builtin_amdgcn_s_barrier();
        }

        // ---- epilogue A: row partials ----
        const int chunk = ci * 4 + wc;
#pragma unroll
        for (int mh = 0; mh < 2; ++mh) {
#pragma unroll
            for (int mi = 0; mi < 4; ++mi) {
#pragma unroll
                for (int reg = 0; reg < 4; ++reg) {
                    const int grow = rbase + wr * 64 + mh * 128 + mi * 16 + (lane >> 4) * 4 + reg;
                    const int posj = (grow - 4096) & (N_ROWS - 1);
                    float vals[4];
                    float rmax = -3.4e38f;
#pragma unroll
                    for (int nf = 0; nf < 4; ++nf) {
                        const int gcol = cbase + wc * 64 + (nf >> 1) * 32 + (nf & 1) * 16 + l15;
                        float logit = acc[mh * 4 + mi][nf][reg] * invT;
                        if (gcol == grow) logit = -9e15f * invT;  // diag mask (diag tiles only)
                        if (gcol == posj) {
                            pos[grow] = logit;   // involution: pos pair covered once, both sides
                            pos[gcol] = logit;
                        }
                        vals[nf] = logit;
                        rmax = fmaxf(rmax, logit);
                    }
#pragma unroll
                    for (int msk = 1; msk < 16; msk <<= 1)
                        rmax = fmaxf(rmax, __shfl_xor(rmax, msk, 64));
                    float s = 0.f;
#pragma unroll
                    for (int nf = 0; nf < 4; ++nf) s += __expf(vals[nf] - rmax);
#pragma unroll
                    for (int msk = 1; msk < 16; msk <<= 1) s += __shfl_xor(s, msk, 64);
                    if (l15 == 0) {
                        part[(size_t)chunk * N_ROWS + grow] = make_float2(rmax, s);
                    }
                }
            }
        }

        // ---- epilogue B: column partials (transpose rows) — off-diag only ----
        if (ri != ci) {
#pragma unroll
            for (int mh = 0; mh < 2; ++mh) {
                const int chunkT = ri * 4 + wr + mh * 2;
#pragma unroll
                for (int nf = 0; nf < 4; ++nf) {
                    const int gcol = cbase + wc * 64 + (nf >> 1) * 32 + (nf & 1) * 16 + l15;
                    float cmax = -3.4e38f;
#pragma unroll
                    for (int mi = 0; mi < 4; ++mi)
#pragma unroll
                        for (int reg = 0; reg < 4; ++reg)
                            cmax = fmaxf(cmax, acc[mh * 4 + mi][nf][reg] * invT);
                    cmax = fmaxf(cmax, __shfl_xor(cmax, 16, 64));
                    cmax = fmaxf(cmax, __shfl_xor(cmax, 32, 64));
                    float cs = 0.f;
#pragma unroll
                    for (int mi = 0; mi < 4; ++mi)
#pragma unroll
                        for (int reg = 0; reg < 4; ++reg)
                            cs += __expf(acc[mh * 4 + mi][nf][reg] * invT - cmax);
                    cs += __shfl_xor(cs, 16, 64);
                    cs += __shfl_xor(cs, 32, 64);
                    if (lane < 16) {
                        part[(size_t)chunkT * N_ROWS + gcol] = make_float2(cmax, cs);
                    }
                }
            }
        }
    } else {
        // ================= STRIP path: 256 rows x 64 cols (tiles 512..527, 4 strips each) =================
        const int s     = blockIdx.x - 512;
        const int id2   = 512 + (s >> 2);
        const int strip = s & 3;
        int ri = 0, rem = id2;
        while (rem >= 32 - ri) { rem -= 32 - ri; ++ri; }
        const int ci = ri + rem;
        const int rbase = ri * BM;
        const int scol  = ci * BN + strip * 64;  // this strip's 64 cols

        char* Ab0 = smem;            // 32 KB
        char* Ab1 = smem + 32768;    // 32 KB
        char* Bb0 = smem + 65536;    //  8 KB
        char* Bb1 = smem + 65536 + 8192;
        float2* colm = (float2*)(smem + 98304);  // [8 waves][64 cols], 4 KB

        const f32x4 zero4 = {0.f, 0.f, 0.f, 0.f};
        f32x4 acc2[2][4];
#pragma unroll
        for (int m = 0; m < 2; ++m)
#pragma unroll
            for (int n = 0; n < 4; ++n) acc2[m][n] = zero4;
        bf16x8 a2[2][2], b2[4][2];

        // prologue: stage kt0 (5 rounds)
        stage_round(zn, rbase + 0,   0, Ab0 + 0,     t);
        stage_round(zn, rbase + 64,  0, Ab0 + 8192,  t);
        stage_round(zn, rbase + 128, 0, Ab0 + 16384, t);
        stage_round(zn, rbase + 192, 0, Ab0 + 24576, t);
        stage_round(zn, scol,        0, Bb0,         t);
        asm volatile("s_waitcnt vmcnt(0)" ::: "memory");
        __builtin_amdgcn_sched_barrier(0);
        __builtin_amdgcn_s_barrier();

        // simple 2-phase loop (T3 minimum): stage(kt+1) || read+MFMA(kt); vmcnt(0); barrier
        for (int kt = 0; kt < NT; ++kt) {
            char* curA = (kt & 1) ? Ab1 : Ab0;
            char* curB = (kt & 1) ? Bb1 : Bb0;
            char* nxtA = (kt & 1) ? Ab0 : Ab1;
            char* nxtB = (kt & 1) ? Bb0 : Bb1;
            if (kt + 1 < NT) {
                const int k1 = (kt + 1) * BK;
                stage_round(zn, rbase + 0,   k1, nxtA + 0,     t);
                stage_round(zn, rbase + 64,  k1, nxtA + 8192,  t);
                stage_round(zn, rbase + 128, k1, nxtA + 16384, t);
                stage_round(zn, rbase + 192, k1, nxtA + 24576, t);
                stage_round(zn, scol,        k1, nxtB,         t);
            }
#pragma unroll
            for (int mi = 0; mi < 2; ++mi)
#pragma unroll
                for (int k = 0; k < 2; ++k)
                    a2[mi][k] = ld_frag(curA, wid * 32 + mi * 16 + l15, k * 64 + kq16, xm);
#pragma unroll
            for (int ni = 0; ni < 4; ++ni)
#pragma unroll
                for (int k = 0; k < 2; ++k)
                    b2[ni][k] = ld_frag(curB, ni * 16 + l15, k * 64 + kq16, xm);
            asm volatile("s_waitcnt lgkmcnt(0)" ::: "memory");
            __builtin_amdgcn_sched_barrier(0);
            __builtin_amdgcn_s_setprio(1);
#pragma unroll
            for (int mi = 0; mi < 2; ++mi)
#pragma unroll
                for (int ni = 0; ni < 4; ++ni)
#pragma unroll
                    for (int k = 0; k < 2; ++k)
                        acc2[mi][ni] = __builtin_amdgcn_mfma_f32_16x16x32_bf16(
                            a2[mi][k], b2[ni][k], acc2[mi][ni], 0, 0, 0);
            __builtin_amdgcn_s_setprio(0);
            asm volatile("s_waitcnt vmcnt(0)" ::: "memory");
            __builtin_amdgcn_sched_barrier(0);
            __builtin_amdgcn_s_barrier();
        }

        // ---- epilogue A: row partials (one chunk, 32 rows per wave) ----
        const int chunk = scol >> 6;
#pragma unroll
        for (int mi = 0; mi < 2; ++mi) {
#pragma unroll
            for (int reg = 0; reg < 4; ++reg) {
                const int grow = rbase + wid * 32 + mi * 16 + (lane >> 4) * 4 + reg;
                const int posj = (grow - 4096) & (N_ROWS - 1);
                float vals[4];
                float rmax = -3.4e38f;
#pragma unroll
                for (int ni = 0; ni < 4; ++ni) {
                    const int gcol = scol + ni * 16 + l15;
                    float logit = acc2[mi][ni][reg] * invT;
                    if (gcol == grow) logit = -9e15f * invT;  // diag tiles cross strips
                    if (gcol == posj) {
                        pos[grow] = logit;
                        pos[gcol] = logit;
                    }
                    vals[ni] = logit;
                    rmax = fmaxf(rmax, logit);
                }
#pragma unroll
                for (int msk = 1; msk < 16; msk <<= 1)
                    rmax = fmaxf(rmax, __shfl_xor(rmax, msk, 64));
                float sum = 0.f;
#pragma unroll
                for (int ni = 0; ni < 4; ++ni) sum += __expf(vals[ni] - rmax);
#pragma unroll
                for (int msk = 1; msk < 16; msk <<= 1) sum += __shfl_xor(sum, msk, 64);
                if (l15 == 0) {
                    part[(size_t)chunk * N_ROWS + grow] = make_float2(rmax, sum);
                }
            }
        }

        // ---- epilogue B: column partials over 4 row-chunks (wave pairs merge via LDS) ----
        if (ri != ci) {
#pragma unroll
            for (int ni = 0; ni < 4; ++ni) {
                float cmax = -3.4e38f;
#pragma unroll
                for (int mi = 0; mi < 2; ++mi)
#pragma unroll
                    for (int reg = 0; reg < 4; ++reg)
                        cmax = fmaxf(cmax, acc2[mi][ni][reg] * invT);
                cmax = fmaxf(cmax, __shfl_xor(cmax, 16, 64));
                cmax = fmaxf(cmax, __shfl_xor(cmax, 32, 64));
                float cs = 0.f;
#pragma unroll
                for (int mi = 0; mi < 2; ++mi)
#pragma unroll
                    for (int reg = 0; reg < 4; ++reg)
                        cs += __expf(acc2[mi][ni][reg] * invT - cmax);
                cs += __shfl_xor(cs, 16, 64);
                cs += __shfl_xor(cs, 32, 64);
                if (lane < 16) {
                    colm[wid * 64 + ni * 16 + lane] = make_float2(cmax, cs);  // 32-row partial
                }
            }
            __syncthreads();
            if ((wid & 1) == 0) {
                const float2 p0 = colm[wid * 64 + lane];
                const float2 p1 = colm[(wid + 1) * 64 + lane];
                const float M = fmaxf(p0.x, p1.x);
                const float S = p0.y * __expf(p0.x - M) + p1.y * __expf(p1.x - M);
                const int chunkT = ri * 4 + (wid >> 1);
                part[(size_t)chunkT * N_ROWS + scol + lane] = make_float2(M, S);
            }
        }
    }
}

// ---------------- Kernel 3: combine partials -> per-block nll sums ----------------
__global__ __launch_bounds__(256) void cl_combine_kernel(
    const float2* __restrict__ part, const float* __restrict__ pos,
    float* __restrict__ bsum) {
    const int r = blockIdx.x * 256 + threadIdx.x;
    float M = -3.4e38f;
#pragma unroll 8
    for (int c = 0; c < 128; ++c) M = fmaxf(M, part[(size_t)c * N_ROWS + r].x);
    float L = 0.f;
#pragma unroll 8
    for (int c = 0; c < 128; ++c) {
        const float2 p = part[(size_t)c * N_ROWS + r];
        L += p.y * __expf(p.x - M);
    }
    float nll = M + logf(L) - pos[r];
    __shared__ float red[4];
#pragma unroll
    for (int msk = 1; msk < 64; msk <<= 1) nll += __shfl_xor(nll, msk, 64);
    if ((threadIdx.x & 63) == 0) red[threadIdx.x >> 6] = nll;
    __syncthreads();
    if (threadIdx.x == 0) bsum[blockIdx.x] = red[0] + red[1] + red[2] + red[3];
}

// ---------------- Kernel 4: final mean ----------------
__global__ void cl_final_kernel(const float* __restrict__ bsum, float* __restrict__ out) {
    const int lane = threadIdx.x;
    float v = (lane < 32) ? bsum[lane] : 0.f;
#pragma unroll
    for (int msk = 1; msk < 64; msk <<= 1) v += __shfl_xor(v, msk, 64);
    if (lane == 0) out[0] = v * (1.0f / (float)N_ROWS);
}

extern "C" void kernel_launch(void* const* d_in, const int* in_sizes, int n_in,
                              void* d_out, int out_size, void* d_ws, size_t ws_size,
                              hipStream_t stream) {
    const float* z = (const float*)d_in[0];
    float* out = (float*)d_out;

    uint8_t* ws = (uint8_t*)d_ws;
    unsigned short* zn = (unsigned short*)ws;                  // 16 MB
    float2* part = (float2*)(ws + ((size_t)16 << 20));         //  8 MB (128*8192*8)
    float* pos   = (float*)(ws + ((size_t)24 << 20));          // 32 KB
    float* bsum  = (float*)(ws + ((size_t)24 << 20) + 32768);  // 128 B

    (void)hipFuncSetAttribute((const void*)cl_simlse8_kernel,
                              hipFuncAttributeMaxDynamicSharedMemorySize, 131072);

    cl_norm_kernel<<<N_ROWS / 4, 256, 0, stream>>>(z, zn);
    cl_simlse8_kernel<<<576, 512, 131072, stream>>>(zn, part, pos);  // 512 full + 64 strips
    cl_combine_kernel<<<N_ROWS / 256, 256, 0, stream>>>(part, pos, bsum);
    cl_final_kernel<<<1, 64, 0, stream>>>(bsum, out);
}